// Round 4
// baseline (150.953 us; speedup 1.0000x reference)
//
#include <hip/hip_runtime.h>

// VQ-VAE VectorQuantizer for MI355X.
// inputs: d_in[0] = inputs [64, 64, 32, 32] fp32 (NCHW), d_in[1] = emb_w [512, 64] fp32
// output d_out (fp32): [loss(1), quantized NCHW (64*64*32*32), idx (65536)]
//
// Correctness: reference computes dist = ||x||^2 + ||e||^2 - 2 x.e in fp32 where
// ||x||^2 ~ 64 quantizes dist to a ~7.6e-6 grid; ~100/65536 points have quantized
// ties resolved by first index. We bit-replicate (numpy pairwise-sum norms,
// sequential-FMA dot over d ascending, fp32 rounding order for dist:
// fma(-2,acc,add_rn(sx,nk)) == add_rn(add_rn(sx,nk), -2*acc) since *2 is exact)
// and tie-break by smallest index. DO NOT reorder this arithmetic.
//
// Perf design (R4): inner loop has ZERO LDS traffic. Codebook rows are
// wave-uniform -> compiler emits s_load_dwordx16 into SGPRs; each lane keeps its
// point's 64 dims in VGPRs (coalesced global load: lane = hw position). 4 waves
// per block split K (128 codes each); 1024 blocks = 4 blocks/CU = 4 waves/SIMD,
// which interleaves the dependent FMA chains at full issue rate.

#define D_    64
#define HW_   1024
#define N_    65536
#define K_    512
#define NDTOT 4194304     // 64*64*32*32
#define PB_   64          // points per block (one per lane)
#define KW_   128         // codes per wave

// ||e_k||^2 in numpy pairwise-summation order (n=64: 8 accumulators, tree combine)
__global__ __launch_bounds__(256) void vq_norm_kernel(const float* __restrict__ emb,
                                                      float* __restrict__ wsn) {
    int k = blockIdx.x * 256 + threadIdx.x;
    if (k < K_) {
        const float* e = emb + k * D_;
        float r[8];
#pragma unroll
        for (int j = 0; j < 8; ++j) r[j] = __fmul_rn(e[j], e[j]);
#pragma unroll
        for (int i = 1; i < 8; ++i)
#pragma unroll
            for (int j = 0; j < 8; ++j)
                r[j] = __fadd_rn(r[j], __fmul_rn(e[i * 8 + j], e[i * 8 + j]));
        wsn[k] = __fadd_rn(__fadd_rn(__fadd_rn(r[0], r[1]), __fadd_rn(r[2], r[3])),
                           __fadd_rn(__fadd_rn(r[4], r[5]), __fadd_rn(r[6], r[7])));
    }
}

__global__ __launch_bounds__(256, 4) void vq_main_kernel(const float* __restrict__ inp,
                                                         const float* __restrict__ emb,
                                                         const float* __restrict__ wsn,
                                                         float* __restrict__ out) {
    __shared__ float sv[4][PB_];
    __shared__ int   si[4][PB_];
    __shared__ int   fi[PB_];

    const int tid  = threadIdx.x;
    const int lane = tid & 63;
    // force wave-uniformity so the k-range (and thus the emb row pointer) is
    // provably uniform -> scalar loads into SGPRs for the codebook row.
    const int wv   = __builtin_amdgcn_readfirstlane(tid >> 6);

    const int n0  = blockIdx.x * PB_;
    const int b   = n0 >> 10;
    const int hw0 = n0 & 1023;
    const float* xcol = inp + b * (D_ * HW_) + hw0 + lane;

    // this lane's point, all 64 dims, in VGPRs (each load is wave-coalesced 256B)
    float x[64];
#pragma unroll
    for (int d = 0; d < D_; ++d) x[d] = xcol[d * HW_];

    // ||x||^2, numpy pairwise order (redundant across the 4 waves; identical value)
    float r[8];
#pragma unroll
    for (int j = 0; j < 8; ++j) r[j] = __fmul_rn(x[j], x[j]);
#pragma unroll
    for (int i = 1; i < 8; ++i)
#pragma unroll
        for (int j = 0; j < 8; ++j)
            r[j] = __fadd_rn(r[j], __fmul_rn(x[i * 8 + j], x[i * 8 + j]));
    const float sx = __fadd_rn(__fadd_rn(__fadd_rn(r[0], r[1]), __fadd_rn(r[2], r[3])),
                               __fadd_rn(__fadd_rn(r[4], r[5]), __fadd_rn(r[6], r[7])));

    // ---- argmin over this wave's 128 codes: pure VALU + SMEM ----
    float runv = 3.4e38f;
    int   runi = 0;
    const int k0 = wv * KW_;
    for (int kk = 0; kk < KW_; ++kk) {
        const int k = k0 + kk;
        const float* e = emb + k * D_;     // uniform -> s_load_dwordx16 x4
        float acc = 0.f;
#pragma unroll
        for (int d = 0; d < D_; ++d)
            acc = fmaf(x[d], e[d], acc);   // sequential, d ascending (numerics!)
        float t1 = __fadd_rn(sx, wsn[k]);  // wsn[k] uniform -> SGPR
        float v  = fmaf(-2.0f, acc, t1);   // == add_rn(t1, -2*acc)
        if (v < runv) { runv = v; runi = k; }  // k ascending, strict < = first idx
    }
    sv[wv][lane] = runv;
    si[wv][lane] = runi;
    __syncthreads();

    // ---- merge the 4 wave-partials (g ascending = k ascending, strict <) ----
    if (tid < PB_) {
        float bv = 3.4e38f; int bi = 0;
#pragma unroll
        for (int g = 0; g < 4; ++g) {
            float v  = sv[g][tid];
            int   ii = si[g][tid];
            if (v < bv) { bv = v; bi = ii; }
        }
        fi[tid] = bi;
        out[1 + NDTOT + n0 + tid] = (float)bi;   // idx as float
    }
    __syncthreads();

    // ---- quantized output + loss: wave 0 only (x already in its registers) ----
    if (wv == 0) {
        const int idx = fi[lane];
        const float4* erow = (const float4*)(emb + idx * D_);  // L2-hot gather
        float* ob = out + 1 + b * (D_ * HW_) + hw0 + lane;     // coalesced stores
        float local = 0.f;
#pragma unroll
        for (int j = 0; j < 16; ++j) {
            float4 e4 = erow[j];
            float ev[4] = {e4.x, e4.y, e4.z, e4.w};
#pragma unroll
            for (int c = 0; c < 4; ++c) {
                float df = ev[c] - x[j * 4 + c];
                local = fmaf(df, df, local);
                ob[(j * 4 + c) * HW_] = ev[c];
            }
        }
#pragma unroll
        for (int off = 32; off > 0; off >>= 1)
            local += __shfl_down(local, off, 64);
        if (lane == 0)
            atomicAdd(out, local * (1.25f / (float)NDTOT));  // loss = 1.25*mean((q-x)^2)
    }
}

extern "C" void kernel_launch(void* const* d_in, const int* in_sizes, int n_in,
                              void* d_out, int out_size, void* d_ws, size_t ws_size,
                              hipStream_t stream) {
    const float* inp = (const float*)d_in[0];
    const float* emb = (const float*)d_in[1];
    float* out = (float*)d_out;
    float* wsn = (float*)d_ws;      // 512 floats: ||e_k||^2

    hipMemsetAsync(d_out, 0, sizeof(float), stream);   // loss accumulator
    vq_norm_kernel<<<2, 256, 0, stream>>>(emb, wsn);
    vq_main_kernel<<<N_ / PB_, 256, 0, stream>>>(inp, emb, wsn, out);
}